// Round 10
// baseline (145.333 us; speedup 1.0000x reference)
//
#include <hip/hip_runtime.h>
#include <hip/hip_bf16.h>
#include <cstddef>

#define B_   2
#define S_   2048
#define HID_ 1152
#define NH_  16
#define NKV_ 4
#define HD_  72
#define MTOT (B_ * S_)   // 4096
#define KVDIM (NKV_ * HD_)  // 288

typedef float f32x4 __attribute__((ext_vector_type(4)));
typedef short bf16x8 __attribute__((ext_vector_type(8)));
typedef short s4v __attribute__((ext_vector_type(4)));

__device__ __forceinline__ float bf2f(short x) {
  unsigned int u = ((unsigned int)(unsigned short)x) << 16;
  return __builtin_bit_cast(float, u);
}
__device__ __forceinline__ short f2bf(float f) {
  unsigned int u = __builtin_bit_cast(unsigned int, f);
  u += 0x7fff + ((u >> 16) & 1);   // RNE
  return (short)(u >> 16);
}

__device__ __forceinline__ void async16(const short* g, short* lds) {
  __builtin_amdgcn_global_load_lds((const __attribute__((address_space(1))) void*)g,
                                   (__attribute__((address_space(3))) void*)lds,
                                   16, 0, 0);
}

// ------- fused fp32 -> bf16 convert (5 tensors) + RoPE cos/sin table, 1 launch -------
__global__ void k_cvt_all(const float4* __restrict__ s0, const float4* __restrict__ s1,
                          const float4* __restrict__ s2, const float4* __restrict__ s3,
                          const float4* __restrict__ s4,
                          s4v* __restrict__ d0, s4v* __restrict__ d1, s4v* __restrict__ d2,
                          s4v* __restrict__ d3, s4v* __restrict__ d4,
                          float2* __restrict__ tab,
                          int n0, int n1, int n2, int n3, int n4t) {
  int ncvt = n0 + n1 + n2 + n3 + n4t;
  int total = ncvt + S_ * 36;
  for (int i = blockIdx.x * blockDim.x + threadIdx.x; i < total;
       i += gridDim.x * blockDim.x) {
    if (i < ncvt) {
      const float4* s;
      s4v* d;
      int off = i;
      if (off < n0) { s = s0; d = d0; }
      else {
        off -= n0;
        if (off < n1) { s = s1; d = d1; }
        else {
          off -= n1;
          if (off < n2) { s = s2; d = d2; }
          else {
            off -= n2;
            if (off < n3) { s = s3; d = d3; }
            else { off -= n3; s = s4; d = d4; }
          }
        }
      }
      float4 v = s[off];
      s4v o = { f2bf(v.x), f2bf(v.y), f2bf(v.z), f2bf(v.w) };
      d[off] = o;
    } else {
      int idx = i - ncvt;
      int ii = idx % 36, s = idx / 36;
      float freq = powf(10000.0f, -(float)ii / 36.0f);
      float a = (float)s * freq;
      tab[idx] = make_float2(cosf(a), sinf(a));
    }
  }
}

// ------- fused post-GEMM: RoPE on Q(16h)+K(4h) and V transpose, 1 launch -------
// Vt[bkv][d(80 pad)][s]; d==72 row = 1.0 so PV-MFMA accumulates the softmax
// denominator for free.
__global__ void k_post(short* __restrict__ Qb, short* __restrict__ Kb,
                       const short* __restrict__ Vb, short* __restrict__ Vt,
                       const float2* __restrict__ tab) {
  int idx = blockIdx.x * blockDim.x + threadIdx.x;
  const int nrope = MTOT * 20 * 36;
  if (idx < nrope) {
    int i = idx % 36;
    int t = idx / 36;
    int hh = t % 20;
    int m = t / 20;
    int s = m & (S_ - 1);
    float2 cs = tab[s * 36 + i];
    short* p = (hh < 16) ? Qb + (size_t)m * HID_ + hh * HD_
                         : Kb + (size_t)m * KVDIM + (hh - 16) * HD_;
    float x1 = bf2f(p[i]), x2 = bf2f(p[i + 36]);
    p[i]      = f2bf(x1 * cs.x - x2 * cs.y);
    p[i + 36] = f2bf(x2 * cs.x + x1 * cs.y);
  } else {
    idx -= nrope;
    if (idx >= 8 * 80 * S_) return;
    int s = idx & (S_ - 1);
    int t2 = idx >> 11;
    int d = t2 % 80;
    int bkv = t2 / 80;
    int b = bkv >> 2, kv = bkv & 3;
    short v = 0;
    if (d < HD_) v = Vb[((size_t)(b * S_ + s)) * KVDIM + kv * HD_ + d];
    else if (d == HD_) v = (short)0x3F80;  // bf16 1.0
    Vt[idx] = v;
  }
}

// ---------------- GEMM common geometry ----------------
#define BM 128
#define BN 128
#define BK 32

// Fused QKV projection: C = X @ [wq;wk;wv]^T over N=1728, one launch.
__global__ __launch_bounds__(256) void k_gemm_qkv(const short* __restrict__ A,
                                                  const short* __restrict__ Wq,
                                                  const short* __restrict__ Wk,
                                                  const short* __restrict__ Wv,
                                                  short* __restrict__ Qo,
                                                  short* __restrict__ Ko,
                                                  short* __restrict__ Vo) {
  const int K = HID_, NTOT = 1728;
  __shared__ short As[BM * BK];
  __shared__ short Bs[BN * BK];
  const int tid = threadIdx.x;
  const int l = tid & 63;
  const int w = tid >> 6;
  const int bm = blockIdx.x * BM;
  const int bn = blockIdx.y * BN;
  const int wr = (w >> 1) * 64;
  const int wc = (w & 1) * 64;
  const int c15 = l & 15, g = l >> 4;
  const int r0 = tid >> 2;
  const int c0 = (tid & 3) * 8;

  f32x4 acc[4][4] = {};

  for (int k0 = 0; k0 < K; k0 += BK) {
#pragma unroll
    for (int it = 0; it < 2; ++it) {
      int ar = bm + it * 64 + r0;
      int br = bn + it * 64 + r0;
      if (br > NTOT - 1) br = NTOT - 1;
      const short* bsrc;
      if (br < 1152)      bsrc = Wq + (size_t)br * K;
      else if (br < 1440) bsrc = Wk + (size_t)(br - 1152) * K;
      else                bsrc = Wv + (size_t)(br - 1440) * K;
      async16(A + (size_t)ar * K + k0 + c0, &As[(it * 64 + r0) * BK + c0]);
      async16(bsrc + k0 + c0, &Bs[(it * 64 + r0) * BK + c0]);
    }
    __syncthreads();
    bf16x8 af[4], bfr[4];
#pragma unroll
    for (int t = 0; t < 4; ++t) {
      af[t]  = *(const bf16x8*)&As[(wr + t * 16 + c15) * BK + g * 8];
      bfr[t] = *(const bf16x8*)&Bs[(wc + t * 16 + c15) * BK + g * 8];
    }
#pragma unroll
    for (int mt = 0; mt < 4; ++mt)
#pragma unroll
      for (int nt = 0; nt < 4; ++nt)
        acc[mt][nt] = __builtin_amdgcn_mfma_f32_16x16x32_bf16(af[mt], bfr[nt], acc[mt][nt], 0, 0, 0);
    __syncthreads();
  }

#pragma unroll
  for (int mt = 0; mt < 4; ++mt)
#pragma unroll
    for (int nt = 0; nt < 4; ++nt)
#pragma unroll
      for (int j = 0; j < 4; ++j) {
        int row = bm + wr + mt * 16 + g * 4 + j;
        int col = bn + wc + nt * 16 + c15;
        short val = f2bf(acc[mt][nt][j]);
        if (col < 1152)      Qo[(size_t)row * HID_ + col] = val;
        else if (col < 1440) Ko[(size_t)row * KVDIM + col - 1152] = val;
        else if (col < NTOT) Vo[(size_t)row * KVDIM + col - 1440] = val;
      }
}

// Output projection: C[M,N] = A[M,K] * B[N,K]^T, fp32 out
__global__ __launch_bounds__(256) void k_gemm_o(const short* __restrict__ A,
                                                const short* __restrict__ Bm,
                                                float* __restrict__ C,
                                                int M, int N, int K) {
  __shared__ short As[BM * BK];
  __shared__ short Bs[BN * BK];
  const int tid = threadIdx.x;
  const int l = tid & 63;
  const int w = tid >> 6;
  const int bm = blockIdx.x * BM;
  const int bn = blockIdx.y * BN;
  const int wr = (w >> 1) * 64;
  const int wc = (w & 1) * 64;
  const int c15 = l & 15, g = l >> 4;
  const int r0 = tid >> 2;
  const int c0 = (tid & 3) * 8;

  f32x4 acc[4][4] = {};

  for (int k0 = 0; k0 < K; k0 += BK) {
#pragma unroll
    for (int it = 0; it < 2; ++it) {
      int ar = bm + it * 64 + r0;
      int br = bn + it * 64 + r0;
      if (br > N - 1) br = N - 1;
      async16(A + (size_t)ar * K + k0 + c0, &As[(it * 64 + r0) * BK + c0]);
      async16(Bm + (size_t)br * K + k0 + c0, &Bs[(it * 64 + r0) * BK + c0]);
    }
    __syncthreads();
    bf16x8 af[4], bfr[4];
#pragma unroll
    for (int t = 0; t < 4; ++t) {
      af[t]  = *(const bf16x8*)&As[(wr + t * 16 + c15) * BK + g * 8];
      bfr[t] = *(const bf16x8*)&Bs[(wc + t * 16 + c15) * BK + g * 8];
    }
#pragma unroll
    for (int mt = 0; mt < 4; ++mt)
#pragma unroll
      for (int nt = 0; nt < 4; ++nt)
        acc[mt][nt] = __builtin_amdgcn_mfma_f32_16x16x32_bf16(af[mt], bfr[nt], acc[mt][nt], 0, 0, 0);
    __syncthreads();
  }

#pragma unroll
  for (int mt = 0; mt < 4; ++mt)
#pragma unroll
    for (int nt = 0; nt < 4; ++nt)
#pragma unroll
      for (int j = 0; j < 4; ++j) {
        int row = bm + wr + mt * 16 + g * 4 + j;
        int col = bn + wc + nt * 16 + c15;
        if (col < N) C[(size_t)row * N + col] = acc[mt][nt][j];
      }
}

// ---------------- Flash attention ----------------
// Block = (b, kv, qt): 4 waves = 4 heads, QB=32 q-rows per wave (2 row-tiles:
// each K/V ds_read feeds 2/4 MFMAs -> LDS-pipe work per FLOP halved vs QB=16;
// the LDS pipe was the saturated resource in R9). SWAPPED QK^T (mfma(K,Q))
// puts q on lane&15 so P packs in-register via v_cvt_pk_bf16_f32 and is
// written as 8 conflict-free ds_write_b32 per row-tile (was 16 4-way-
// conflicting b16 writes). P scratch aliases the dead K buffer. Fixed-shift
// softmax; denominator via ones-row of V^T through the PV MFMA.
#define QB 32
#define KT 64

__global__ __launch_bounds__(256, 2) void k_flash(const short* __restrict__ Q,
                                                  const short* __restrict__ Kg,
                                                  const short* __restrict__ Vt,
                                                  short* __restrict__ O) {
  const int bid = blockIdx.x;
  const int bkv = bid & 7;            // one (b,kv) per XCD -> K/V L2-resident
  const int qt = 63 - (bid >> 3);     // longest blocks first
  const int b = bkv >> 2, kv = bkv & 3;
  const int tid = threadIdx.x;
  const int w = tid >> 6, l = tid & 63;
  const int h = kv * 4 + w;
  const int q0 = qt * QB;
  const int c15 = l & 15, g = l >> 4;

  // 38912 B: double-buffered Ks[64][72] + Vs[80][64] (shorts).
  // P (per-wave 16 rows x 72 stride) aliases the CURRENT Ks after QK^T.
  __shared__ short lds[19456];
  short* Ks0 = lds;
  short* Vs0 = lds + 4608;
  short* Ks1 = lds + 9728;
  short* Vs1 = lds + 14336;

  const float SCL = 0.117851130f * 1.4426950408889634f;  // 1/sqrt(72)*log2(e)
  const float SHIFT = 8.0f;  // fixed exponent shift (cancels in final divide)

  const short* Qbase = Q + (size_t)(b * S_) * HID_ + h * HD_;
  const short* Kbase = Kg + (size_t)(b * S_) * KVDIM + kv * HD_;
  const short* Vbase = Vt + (size_t)bkv * 80 * S_;

  // Q fragments (B-operand now), pre-scaled; hd padded 72->96 with zero frags
  bf16x8 qf[2][3];
  const bf16x8 zfrag = {0, 0, 0, 0, 0, 0, 0, 0};
#pragma unroll
  for (int rt = 0; rt < 2; ++rt) {
    int row = q0 + rt * 16 + c15;
#pragma unroll
    for (int ks = 0; ks < 3; ++ks) {
      int d0 = ks * 32 + g * 8;
      qf[rt][ks] = (d0 < HD_) ? *(const bf16x8*)(Qbase + (size_t)row * HID_ + d0) : zfrag;
    }
#pragma unroll
    for (int ks = 0; ks < 3; ++ks)
#pragma unroll
      for (int e = 0; e < 8; ++e)
        qf[rt][ks][e] = f2bf(bf2f(qf[rt][ks][e]) * SCL);
  }

  f32x4 accO[2][5] = {};

  const int nkt = (qt + 2) >> 1;          // ceil((qt+1)*32/64)
  const int nfull = (QB * qt + 1) >> 6;   // tiles with no masked element

  // cooperative stage: K = 576 16B-chunks, V = 640 16B-chunks, 256 threads
  auto STAGE = [&](int kb, short* Kd, short* Vd) {
    const short* kp = Kbase + (size_t)kb * KVDIM;
    const short* vp = Vbase + kb;
#pragma unroll
    for (int i = 0; i < 5; ++i) {
      int c = tid + 256 * i;
      if (c < 576) {
        int row = c / 9, cc = c - row * 9;
        async16(kp + (size_t)row * KVDIM + cc * 8, &Kd[c * 8]);
      } else if (c < 1216) {
        int c2 = c - 576;
        int row = c2 >> 3, slot = c2 & 7;
        async16(vp + (size_t)row * S_ + ((slot ^ (row & 7)) << 3), &Vd[c2 * 8]);
      }
    }
  };

  STAGE(0, Ks0, Vs0);
  short *Ksc = Ks0, *Vsc = Vs0, *Ksn = Ks1, *Vsn = Vs1;

  for (int kt = 0; kt < nkt; ++kt) {
    // own share of STAGE(kt) drained, then block-wide visibility
    asm volatile("s_waitcnt vmcnt(0)" ::: "memory");
    __builtin_amdgcn_sched_barrier(0);
    __syncthreads();
    // prefetch next tile into the other buffer; flies during this tile's compute
    if (kt + 1 < nkt) STAGE((kt + 1) * KT, Ksn, Vsn);

    const int kbase = kt * KT;

    // ---- swapped QK^T: S^T = K x Q  (lane: q = c15, k = ct*16 + g*4 + j) ----
    f32x4 sc0[4] = {}, sc1[4] = {};
    __builtin_amdgcn_s_setprio(1);
#pragma unroll
    for (int ct = 0; ct < 4; ++ct)
#pragma unroll
      for (int ks = 0; ks < 3; ++ks) {
        bf16x8 kf = *(const bf16x8*)&Ksc[(ct * 16 + c15) * 72 + ks * 32 + g * 8];
        sc0[ct] = __builtin_amdgcn_mfma_f32_16x16x32_bf16(kf, qf[0][ks], sc0[ct], 0, 0, 0);
        sc1[ct] = __builtin_amdgcn_mfma_f32_16x16x32_bf16(kf, qf[1][ks], sc1[ct], 0, 0, 0);
      }
    __builtin_amdgcn_s_setprio(0);

    // ---- mask + fixed-shift exp2 + in-register bf16 pack ----
    unsigned int pk0[8], pk1[8];
    {
      const int qrow = q0 + c15;
      if (kt >= nfull) {
#pragma unroll
        for (int ct = 0; ct < 4; ++ct) {
          int kc = kbase + ct * 16 + g * 4;
#pragma unroll
          for (int j = 0; j < 4; ++j)
            if (kc + j > qrow) sc0[ct][j] = -1e30f;
        }
      }
#pragma unroll
      for (int ct = 0; ct < 4; ++ct)
#pragma unroll
        for (int j = 0; j < 4; ++j)
          sc0[ct][j] = exp2f(sc0[ct][j] - SHIFT);
#pragma unroll
      for (int ct = 0; ct < 4; ++ct)
#pragma unroll
        for (int h2 = 0; h2 < 2; ++h2)
          asm("v_cvt_pk_bf16_f32 %0, %1, %2"
              : "=v"(pk0[ct * 2 + h2])
              : "v"(sc0[ct][2 * h2]), "v"(sc0[ct][2 * h2 + 1]));
    }
    {
      const int qrow = q0 + 16 + c15;
      if (kt >= nfull) {
#pragma unroll
        for (int ct = 0; ct < 4; ++ct) {
          int kc = kbase + ct * 16 + g * 4;
#pragma unroll
          for (int j = 0; j < 4; ++j)
            if (kc + j > qrow) sc1[ct][j] = -1e30f;
        }
      }
#pragma unroll
      for (int ct = 0; ct < 4; ++ct)
#pragma unroll
        for (int j = 0; j < 4; ++j)
          sc1[ct][j] = exp2f(sc1[ct][j] - SHIFT);
#pragma unroll
      for (int ct = 0; ct < 4; ++ct)
#pragma unroll
        for (int h2 = 0; h2 < 2; ++h2)
          asm("v_cvt_pk_bf16_f32 %0, %1, %2"
              : "=v"(pk1[ct * 2 + h2])
              : "v"(sc1[ct][2 * h2]), "v"(sc1[ct][2 * h2 + 1]));
    }

    // ---- all waves done reading Ksc -> safe to overwrite with P ----
    __syncthreads();
    unsigned int* Pw = (unsigned int*)(Ksc + w * 1152);  // per-wave 2304 B
    const short* Pr = (const short*)Pw;
    const int pwb = c15 * 36 + g * 2;
    bf16x8 pa00, pa01, pa10, pa11;
    // rt0: 8 conflict-free b32 writes, then 2 b128 reads (A-frag layout)
#pragma unroll
    for (int ct = 0; ct < 4; ++ct) {
      Pw[pwb + ct * 8]     = pk0[ct * 2];
      Pw[pwb + ct * 8 + 1] = pk0[ct * 2 + 1];
    }
    asm volatile("s_waitcnt lgkmcnt(0)" ::: "memory");
    __builtin_amdgcn_sched_barrier(0);
    pa00 = *(const bf16x8*)&Pr[c15 * 72 + g * 8];
    pa01 = *(const bf16x8*)&Pr[c15 * 72 + 32 + g * 8];
    asm volatile("s_waitcnt lgkmcnt(0)" ::: "memory");
    __builtin_amdgcn_sched_barrier(0);
    // rt1 reuses the same region (reads above retired)
#pragma unroll
    for (int ct = 0; ct < 4; ++ct) {
      Pw[pwb + ct * 8]     = pk1[ct * 2];
      Pw[pwb + ct * 8 + 1] = pk1[ct * 2 + 1];
    }
    asm volatile("s_waitcnt lgkmcnt(0)" ::: "memory");
    __builtin_amdgcn_sched_barrier(0);
    pa10 = *(const bf16x8*)&Pr[c15 * 72 + g * 8];
    pa11 = *(const bf16x8*)&Pr[c15 * 72 + 32 + g * 8];

    // ---- PV: V frags read once, shared by both row-tiles ----
    __builtin_amdgcn_s_setprio(1);
#pragma unroll
    for (int dt = 0; dt < 5; ++dt) {
      int vrow = dt * 16 + c15;
      bf16x8 vb0 = *(const bf16x8*)&Vsc[vrow * 64 + (((0 + g) ^ (vrow & 7)) << 3)];
      bf16x8 vb1 = *(const bf16x8*)&Vsc[vrow * 64 + (((4 + g) ^ (vrow & 7)) << 3)];
      accO[0][dt] = __builtin_amdgcn_mfma_f32_16x16x32_bf16(pa00, vb0, accO[0][dt], 0, 0, 0);
      accO[0][dt] = __builtin_amdgcn_mfma_f32_16x16x32_bf16(pa01, vb1, accO[0][dt], 0, 0, 0);
      accO[1][dt] = __builtin_amdgcn_mfma_f32_16x16x32_bf16(pa10, vb0, accO[1][dt], 0, 0, 0);
      accO[1][dt] = __builtin_amdgcn_mfma_f32_16x16x32_bf16(pa11, vb1, accO[1][dt], 0, 0, 0);
    }
    __builtin_amdgcn_s_setprio(0);

    short* t1 = Ksc; Ksc = Ksn; Ksn = t1;
    short* t2 = Vsc; Vsc = Vsn; Vsn = t2;
  }

  // ---- epilogue: denominator from ones-row (accO[rt][4] @ c15==8), write O ----
#pragma unroll
  for (int rt = 0; rt < 2; ++rt) {
    float lj[4];
#pragma unroll
    for (int j = 0; j < 4; ++j)
      lj[j] = 1.0f / __shfl(accO[rt][4][j], (l & 48) | 8);
#pragma unroll
    for (int dt = 0; dt < 5; ++dt) {
      int d = dt * 16 + c15;
      if (d < HD_) {
#pragma unroll
        for (int j = 0; j < 4; ++j) {
          int row = q0 + rt * 16 + g * 4 + j;
          O[(size_t)(b * S_ + row) * HID_ + h * HD_ + d] = f2bf(accO[rt][dt][j] * lj[j]);
        }
      }
    }
  }
}

// ---------------- host ----------------
extern "C" void kernel_launch(void* const* d_in, const int* in_sizes, int n_in,
                              void* d_out, int out_size, void* d_ws, size_t ws_size,
                              hipStream_t stream) {
  const float* hs = (const float*)d_in[0];
  // d_in[1] = attention_mask (causal, implemented analytically — unused)
  const float* wq = (const float*)d_in[2];
  const float* wk = (const float*)d_in[3];
  const float* wv = (const float*)d_in[4];
  const float* wo = (const float*)d_in[5];

  char* ws = (char*)d_ws;
  short* Xb  = (short*)(ws + 0);          // 4096x1152 bf16
  short* Qb  = (short*)(ws + 9437184);    // 4096x1152
  short* Kb  = (short*)(ws + 18874368);   // 4096x288
  short* Vb  = (short*)(ws + 21233664);   // 4096x288
  short* Vt  = (short*)(ws + 23592960);   // 8x80x2048
  short* Ob  = (short*)(ws + 26214400);   // 4096x1152
  short* wqb = (short*)(ws + 35651584);   // 1152x1152
  short* wkb = (short*)(ws + 38305792);   // 288x1152
  short* wvb = (short*)(ws + 38969344);   // 288x1152
  short* wob = (short*)(ws + 39632896);   // 1152x1152
  float2* tab = (float2*)(ws + 42287104); // 2048x36 cos/sin

  // fused convert (hs + 4 weights) + RoPE table, one launch
  k_cvt_all<<<2048, 256, 0, stream>>>(
      (const float4*)hs, (const float4*)wq, (const float4*)wk, (const float4*)wv,
      (const float4*)wo,
      (s4v*)Xb, (s4v*)wqb, (s4v*)wkb, (s4v*)wvb, (s4v*)wob, tab,
      MTOT * HID_ / 4, HID_ * HID_ / 4, KVDIM * HID_ / 4, KVDIM * HID_ / 4,
      HID_ * HID_ / 4);

  // fused QKV projection (N = 1152+288+288 = 1728)
  k_gemm_qkv<<<dim3(32, 14), 256, 0, stream>>>(Xb, wqb, wkb, wvb, Qb, Kb, Vb);

  // fused RoPE (Q+K) + V transpose, one launch
  {
    int total = MTOT * 20 * 36 + 8 * 80 * S_;
    k_post<<<(total + 255) / 256, 256, 0, stream>>>(Qb, Kb, Vb, Vt, tab);
  }

  k_flash<<<512, 256, 0, stream>>>(Qb, Kb, Vt, Ob);

  k_gemm_o<<<dim3(32, 9), 256, 0, stream>>>(Ob, wob, (float*)d_out, MTOT, HID_, HID_);
}

// Round 11
// 131.846 us; speedup vs baseline: 1.1023x; 1.1023x over previous
//
#include <hip/hip_runtime.h>
#include <hip/hip_bf16.h>
#include <cstddef>

#define B_   2
#define S_   2048
#define HID_ 1152
#define NH_  16
#define NKV_ 4
#define HD_  72
#define MTOT (B_ * S_)   // 4096
#define KVDIM (NKV_ * HD_)  // 288

typedef float f32x4 __attribute__((ext_vector_type(4)));
typedef short bf16x8 __attribute__((ext_vector_type(8)));
typedef short s4v __attribute__((ext_vector_type(4)));

__device__ __forceinline__ float bf2f(short x) {
  unsigned int u = ((unsigned int)(unsigned short)x) << 16;
  return __builtin_bit_cast(float, u);
}
__device__ __forceinline__ short f2bf(float f) {
  unsigned int u = __builtin_bit_cast(unsigned int, f);
  u += 0x7fff + ((u >> 16) & 1);   // RNE
  return (short)(u >> 16);
}

// hardware v_exp_f32 (2^x). Without -ffast-math, exp2f() lowers to the
// precise OCML sequence (~25 VALU ops) — this is 1 op, and sits on the
// flash kernel's serial softmax chain.
__device__ __forceinline__ float fast_exp2(float x) {
#if __has_builtin(__builtin_amdgcn_exp2f)
  return __builtin_amdgcn_exp2f(x);
#else
  return exp2f(x);
#endif
}

__device__ __forceinline__ void async16(const short* g, short* lds) {
  __builtin_amdgcn_global_load_lds((const __attribute__((address_space(1))) void*)g,
                                   (__attribute__((address_space(3))) void*)lds,
                                   16, 0, 0);
}

// ------- fused fp32 -> bf16 convert (5 tensors) + RoPE cos/sin table, 1 launch -------
__global__ void k_cvt_all(const float4* __restrict__ s0, const float4* __restrict__ s1,
                          const float4* __restrict__ s2, const float4* __restrict__ s3,
                          const float4* __restrict__ s4,
                          s4v* __restrict__ d0, s4v* __restrict__ d1, s4v* __restrict__ d2,
                          s4v* __restrict__ d3, s4v* __restrict__ d4,
                          float2* __restrict__ tab,
                          int n0, int n1, int n2, int n3, int n4t) {
  int ncvt = n0 + n1 + n2 + n3 + n4t;
  int total = ncvt + S_ * 36;
  for (int i = blockIdx.x * blockDim.x + threadIdx.x; i < total;
       i += gridDim.x * blockDim.x) {
    if (i < ncvt) {
      const float4* s;
      s4v* d;
      int off = i;
      if (off < n0) { s = s0; d = d0; }
      else {
        off -= n0;
        if (off < n1) { s = s1; d = d1; }
        else {
          off -= n1;
          if (off < n2) { s = s2; d = d2; }
          else {
            off -= n2;
            if (off < n3) { s = s3; d = d3; }
            else { off -= n3; s = s4; d = d4; }
          }
        }
      }
      float4 v = s[off];
      s4v o = { f2bf(v.x), f2bf(v.y), f2bf(v.z), f2bf(v.w) };
      d[off] = o;
    } else {
      int idx = i - ncvt;
      int ii = idx % 36, s = idx / 36;
      float freq = powf(10000.0f, -(float)ii / 36.0f);
      float a = (float)s * freq;
      tab[idx] = make_float2(cosf(a), sinf(a));
    }
  }
}

// ------- fused post-GEMM: RoPE on Q(16h)+K(4h) and V transpose, 1 launch -------
// Vt[bkv][d(80 pad)][s]; d==72 row = 1.0 so PV-MFMA accumulates the softmax
// denominator for free.
__global__ void k_post(short* __restrict__ Qb, short* __restrict__ Kb,
                       const short* __restrict__ Vb, short* __restrict__ Vt,
                       const float2* __restrict__ tab) {
  int idx = blockIdx.x * blockDim.x + threadIdx.x;
  const int nrope = MTOT * 20 * 36;
  if (idx < nrope) {
    int i = idx % 36;
    int t = idx / 36;
    int hh = t % 20;
    int m = t / 20;
    int s = m & (S_ - 1);
    float2 cs = tab[s * 36 + i];
    short* p = (hh < 16) ? Qb + (size_t)m * HID_ + hh * HD_
                         : Kb + (size_t)m * KVDIM + (hh - 16) * HD_;
    float x1 = bf2f(p[i]), x2 = bf2f(p[i + 36]);
    p[i]      = f2bf(x1 * cs.x - x2 * cs.y);
    p[i + 36] = f2bf(x2 * cs.x + x1 * cs.y);
  } else {
    idx -= nrope;
    if (idx >= 8 * 80 * S_) return;
    int s = idx & (S_ - 1);
    int t2 = idx >> 11;
    int d = t2 % 80;
    int bkv = t2 / 80;
    int b = bkv >> 2, kv = bkv & 3;
    short v = 0;
    if (d < HD_) v = Vb[((size_t)(b * S_ + s)) * KVDIM + kv * HD_ + d];
    else if (d == HD_) v = (short)0x3F80;  // bf16 1.0
    Vt[idx] = v;
  }
}

// ---------------- GEMM common geometry ----------------
#define BM 128
#define BN 128
#define BK 32

// Fused QKV projection: C = X @ [wq;wk;wv]^T over N=1728, one launch.
__global__ __launch_bounds__(256) void k_gemm_qkv(const short* __restrict__ A,
                                                  const short* __restrict__ Wq,
                                                  const short* __restrict__ Wk,
                                                  const short* __restrict__ Wv,
                                                  short* __restrict__ Qo,
                                                  short* __restrict__ Ko,
                                                  short* __restrict__ Vo) {
  const int K = HID_, NTOT = 1728;
  __shared__ short As[BM * BK];
  __shared__ short Bs[BN * BK];
  const int tid = threadIdx.x;
  const int l = tid & 63;
  const int w = tid >> 6;
  const int bm = blockIdx.x * BM;
  const int bn = blockIdx.y * BN;
  const int wr = (w >> 1) * 64;
  const int wc = (w & 1) * 64;
  const int c15 = l & 15, g = l >> 4;
  const int r0 = tid >> 2;
  const int c0 = (tid & 3) * 8;

  f32x4 acc[4][4] = {};

  for (int k0 = 0; k0 < K; k0 += BK) {
#pragma unroll
    for (int it = 0; it < 2; ++it) {
      int ar = bm + it * 64 + r0;
      int br = bn + it * 64 + r0;
      if (br > NTOT - 1) br = NTOT - 1;
      const short* bsrc;
      if (br < 1152)      bsrc = Wq + (size_t)br * K;
      else if (br < 1440) bsrc = Wk + (size_t)(br - 1152) * K;
      else                bsrc = Wv + (size_t)(br - 1440) * K;
      async16(A + (size_t)ar * K + k0 + c0, &As[(it * 64 + r0) * BK + c0]);
      async16(bsrc + k0 + c0, &Bs[(it * 64 + r0) * BK + c0]);
    }
    __syncthreads();
    bf16x8 af[4], bfr[4];
#pragma unroll
    for (int t = 0; t < 4; ++t) {
      af[t]  = *(const bf16x8*)&As[(wr + t * 16 + c15) * BK + g * 8];
      bfr[t] = *(const bf16x8*)&Bs[(wc + t * 16 + c15) * BK + g * 8];
    }
#pragma unroll
    for (int mt = 0; mt < 4; ++mt)
#pragma unroll
      for (int nt = 0; nt < 4; ++nt)
        acc[mt][nt] = __builtin_amdgcn_mfma_f32_16x16x32_bf16(af[mt], bfr[nt], acc[mt][nt], 0, 0, 0);
    __syncthreads();
  }

#pragma unroll
  for (int mt = 0; mt < 4; ++mt)
#pragma unroll
    for (int nt = 0; nt < 4; ++nt)
#pragma unroll
      for (int j = 0; j < 4; ++j) {
        int row = bm + wr + mt * 16 + g * 4 + j;
        int col = bn + wc + nt * 16 + c15;
        short val = f2bf(acc[mt][nt][j]);
        if (col < 1152)      Qo[(size_t)row * HID_ + col] = val;
        else if (col < 1440) Ko[(size_t)row * KVDIM + col - 1152] = val;
        else if (col < NTOT) Vo[(size_t)row * KVDIM + col - 1440] = val;
      }
}

// Output projection: C[M,N] = A[M,K] * B[N,K]^T, fp32 out
__global__ __launch_bounds__(256) void k_gemm_o(const short* __restrict__ A,
                                                const short* __restrict__ Bm,
                                                float* __restrict__ C,
                                                int M, int N, int K) {
  __shared__ short As[BM * BK];
  __shared__ short Bs[BN * BK];
  const int tid = threadIdx.x;
  const int l = tid & 63;
  const int w = tid >> 6;
  const int bm = blockIdx.x * BM;
  const int bn = blockIdx.y * BN;
  const int wr = (w >> 1) * 64;
  const int wc = (w & 1) * 64;
  const int c15 = l & 15, g = l >> 4;
  const int r0 = tid >> 2;
  const int c0 = (tid & 3) * 8;

  f32x4 acc[4][4] = {};

  for (int k0 = 0; k0 < K; k0 += BK) {
#pragma unroll
    for (int it = 0; it < 2; ++it) {
      int ar = bm + it * 64 + r0;
      int br = bn + it * 64 + r0;
      if (br > N - 1) br = N - 1;
      async16(A + (size_t)ar * K + k0 + c0, &As[(it * 64 + r0) * BK + c0]);
      async16(Bm + (size_t)br * K + k0 + c0, &Bs[(it * 64 + r0) * BK + c0]);
    }
    __syncthreads();
    bf16x8 af[4], bfr[4];
#pragma unroll
    for (int t = 0; t < 4; ++t) {
      af[t]  = *(const bf16x8*)&As[(wr + t * 16 + c15) * BK + g * 8];
      bfr[t] = *(const bf16x8*)&Bs[(wc + t * 16 + c15) * BK + g * 8];
    }
#pragma unroll
    for (int mt = 0; mt < 4; ++mt)
#pragma unroll
      for (int nt = 0; nt < 4; ++nt)
        acc[mt][nt] = __builtin_amdgcn_mfma_f32_16x16x32_bf16(af[mt], bfr[nt], acc[mt][nt], 0, 0, 0);
    __syncthreads();
  }

#pragma unroll
  for (int mt = 0; mt < 4; ++mt)
#pragma unroll
    for (int nt = 0; nt < 4; ++nt)
#pragma unroll
      for (int j = 0; j < 4; ++j) {
        int row = bm + wr + mt * 16 + g * 4 + j;
        int col = bn + wc + nt * 16 + c15;
        if (col < N) C[(size_t)row * N + col] = acc[mt][nt][j];
      }
}

// ---------------- Flash attention (R7 structure + hw exp2) ----------------
// Block = (b, kv, qt): 4 waves = the 4 q-heads sharing this kv group. K/V
// staged once per block into double-buffered LDS via global_load_lds;
// prefetch issued right after the per-tile barrier so DMA latency hides under
// tile-t compute. One __syncthreads per tile. Fixed-shift softmax
// (P = 2^(s-8), no running max, no cross-lane reduce) via hardware v_exp_f32;
// denominator accumulated by the all-ones V^T row d=72 through the PV MFMA.
#define QB 16
#define KT 64

__global__ __launch_bounds__(256, 2) void k_flash(const short* __restrict__ Q,
                                                  const short* __restrict__ Kg,
                                                  const short* __restrict__ Vt,
                                                  short* __restrict__ O) {
  const int bid = blockIdx.x;
  const int bkv = bid & 7;            // one (b,kv) per XCD -> K/V L2-resident
  const int qt = 127 - (bid >> 3);    // longest blocks first
  const int b = bkv >> 2, kv = bkv & 3;
  const int tid = threadIdx.x;
  const int w = tid >> 6, l = tid & 63;
  const int h = kv * 4 + w;
  const int q0 = qt * QB;
  const int c15 = l & 15, g = l >> 4;

  // 48128 B -> 3 blocks/CU.
  // Ks [64][72] shorts; Vs [80][64] shorts (XOR-swizzled slots); x2 buffers;
  // Ps: per-wave 16x72 P scratch (private -> no inter-wave race).
  __shared__ short lds[24064];
  short* Ks0 = lds;
  short* Vs0 = lds + 4608;
  short* Ks1 = lds + 9728;
  short* Vs1 = lds + 14336;
  short* Ps  = lds + 19456 + w * 1152;

  const float SCL = 0.117851130f * 1.4426950408889634f;  // 1/sqrt(72)*log2(e)
  const float SHIFT = 8.0f;  // fixed exponent shift (cancels in final divide)

  const short* Qbase = Q + (size_t)(b * S_) * HID_ + h * HD_;
  const short* Kbase = Kg + (size_t)(b * S_) * KVDIM + kv * HD_;
  const short* Vbase = Vt + (size_t)bkv * 80 * S_;

  // Q fragments, pre-scaled (hd padded 72->96 with zero frags)
  bf16x8 qf[3];
  const bf16x8 zfrag = {0, 0, 0, 0, 0, 0, 0, 0};
  {
    int row = q0 + c15;
#pragma unroll
    for (int ks = 0; ks < 3; ++ks) {
      int d0 = ks * 32 + g * 8;
      qf[ks] = (d0 < HD_) ? *(const bf16x8*)(Qbase + (size_t)row * HID_ + d0) : zfrag;
    }
#pragma unroll
    for (int ks = 0; ks < 3; ++ks)
#pragma unroll
      for (int e = 0; e < 8; ++e)
        qf[ks][e] = f2bf(bf2f(qf[ks][e]) * SCL);
  }

  f32x4 accO[5] = {};

  const int nkt = (q0 + QB + KT - 1) / KT;
  const int nfull = (QB * qt + 1) >> 6;   // tiles with no masked element

  // cooperative stage: K = 576 16B-chunks, V = 640 16B-chunks, 256 threads
  auto STAGE = [&](int kb, short* Kd, short* Vd) {
    const short* kp = Kbase + (size_t)kb * KVDIM;
    const short* vp = Vbase + kb;
#pragma unroll
    for (int i = 0; i < 5; ++i) {
      int c = tid + 256 * i;
      if (c < 576) {
        int row = c / 9, cc = c - row * 9;
        async16(kp + (size_t)row * KVDIM + cc * 8, &Kd[c * 8]);
      } else if (c < 1216) {
        int c2 = c - 576;
        int row = c2 >> 3, slot = c2 & 7;
        async16(vp + (size_t)row * S_ + ((slot ^ (row & 7)) << 3), &Vd[c2 * 8]);
      }
    }
  };

  STAGE(0, Ks0, Vs0);
  short *Ksc = Ks0, *Vsc = Vs0, *Ksn = Ks1, *Vsn = Vs1;

  for (int kt = 0; kt < nkt; ++kt) {
    // own share of STAGE(kt) drained, then block-wide visibility
    asm volatile("s_waitcnt vmcnt(0)" ::: "memory");
    __builtin_amdgcn_sched_barrier(0);
    __syncthreads();
    // prefetch next tile into the other buffer; flies during this tile's compute
    if (kt + 1 < nkt) STAGE((kt + 1) * KT, Ksn, Vsn);

    const int kbase = kt * KT;

    // ---- QK^T from shared Ks ----
    f32x4 sc[4] = {};
    __builtin_amdgcn_s_setprio(1);
#pragma unroll
    for (int ct = 0; ct < 4; ++ct)
#pragma unroll
      for (int ks = 0; ks < 3; ++ks) {
        bf16x8 kf = *(const bf16x8*)&Ksc[(ct * 16 + c15) * 72 + ks * 32 + g * 8];
        sc[ct] = __builtin_amdgcn_mfma_f32_16x16x32_bf16(qf[ks], kf, sc[ct], 0, 0, 0);
      }
    __builtin_amdgcn_s_setprio(0);

    // ---- mask + fixed-shift exp2 (hw v_exp_f32, no max, no reduce) ----
    const int qrow = q0 + g * 4;  // + j
    if (kt >= nfull) {
#pragma unroll
      for (int ct = 0; ct < 4; ++ct) {
        int col = kbase + ct * 16 + c15;
#pragma unroll
        for (int j = 0; j < 4; ++j)
          if (col > qrow + j) sc[ct][j] = -1e30f;
      }
    }
#pragma unroll
    for (int ct = 0; ct < 4; ++ct)
#pragma unroll
      for (int j = 0; j < 4; ++j)
        sc[ct][j] = fast_exp2(sc[ct][j] - SHIFT);

    // ---- P: D-layout -> A-frag layout via private LDS scratch ----
#pragma unroll
    for (int ct = 0; ct < 4; ++ct)
#pragma unroll
      for (int j = 0; j < 4; ++j)
        Ps[(g * 4 + j) * 72 + ct * 16 + c15] = f2bf(sc[ct][j]);
    asm volatile("s_waitcnt lgkmcnt(0)" ::: "memory");
    __builtin_amdgcn_sched_barrier(0);
    bf16x8 pa0 = *(const bf16x8*)&Ps[c15 * 72 + g * 8];
    bf16x8 pa1 = *(const bf16x8*)&Ps[c15 * 72 + 32 + g * 8];

    // ---- PV from shared Vs ----
    __builtin_amdgcn_s_setprio(1);
#pragma unroll
    for (int dt = 0; dt < 5; ++dt) {
      int vrow = dt * 16 + c15;
      bf16x8 vb0 = *(const bf16x8*)&Vsc[vrow * 64 + (((0 * 4 + g) ^ (vrow & 7)) << 3)];
      bf16x8 vb1 = *(const bf16x8*)&Vsc[vrow * 64 + (((1 * 4 + g) ^ (vrow & 7)) << 3)];
      accO[dt] = __builtin_amdgcn_mfma_f32_16x16x32_bf16(pa0, vb0, accO[dt], 0, 0, 0);
      accO[dt] = __builtin_amdgcn_mfma_f32_16x16x32_bf16(pa1, vb1, accO[dt], 0, 0, 0);
    }
    __builtin_amdgcn_s_setprio(0);

    short* t1 = Ksc; Ksc = Ksn; Ksn = t1;
    short* t2 = Vsc; Vsc = Vsn; Vsn = t2;
  }

  // ---- epilogue: denominator from ones-row (accO[4] @ c15==8), then write ----
  float lj[4];
#pragma unroll
  for (int j = 0; j < 4; ++j)
    lj[j] = 1.0f / __shfl(accO[4][j], (l & 48) | 8);
#pragma unroll
  for (int dt = 0; dt < 5; ++dt) {
    int d = dt * 16 + c15;
    if (d < HD_) {
#pragma unroll
      for (int j = 0; j < 4; ++j) {
        int row = q0 + g * 4 + j;
        O[(size_t)(b * S_ + row) * HID_ + h * HD_ + d] = f2bf(accO[dt][j] * lj[j]);
      }
    }
  }
}

// ---------------- host ----------------
extern "C" void kernel_launch(void* const* d_in, const int* in_sizes, int n_in,
                              void* d_out, int out_size, void* d_ws, size_t ws_size,
                              hipStream_t stream) {
  const float* hs = (const float*)d_in[0];
  // d_in[1] = attention_mask (causal, implemented analytically — unused)
  const float* wq = (const float*)d_in[2];
  const float* wk = (const float*)d_in[3];
  const float* wv = (const float*)d_in[4];
  const float* wo = (const float*)d_in[5];

  char* ws = (char*)d_ws;
  short* Xb  = (short*)(ws + 0);          // 4096x1152 bf16
  short* Qb  = (short*)(ws + 9437184);    // 4096x1152
  short* Kb  = (short*)(ws + 18874368);   // 4096x288
  short* Vb  = (short*)(ws + 21233664);   // 4096x288
  short* Vt  = (short*)(ws + 23592960);   // 8x80x2048
  short* Ob  = (short*)(ws + 26214400);   // 4096x1152
  short* wqb = (short*)(ws + 35651584);   // 1152x1152
  short* wkb = (short*)(ws + 38305792);   // 288x1152
  short* wvb = (short*)(ws + 38969344);   // 288x1152
  short* wob = (short*)(ws + 39632896);   // 1152x1152
  float2* tab = (float2*)(ws + 42287104); // 2048x36 cos/sin

  // fused convert (hs + 4 weights) + RoPE table, one launch
  k_cvt_all<<<2048, 256, 0, stream>>>(
      (const float4*)hs, (const float4*)wq, (const float4*)wk, (const float4*)wv,
      (const float4*)wo,
      (s4v*)Xb, (s4v*)wqb, (s4v*)wkb, (s4v*)wvb, (s4v*)wob, tab,
      MTOT * HID_ / 4, HID_ * HID_ / 4, KVDIM * HID_ / 4, KVDIM * HID_ / 4,
      HID_ * HID_ / 4);

  // fused QKV projection (N = 1152+288+288 = 1728)
  k_gemm_qkv<<<dim3(32, 14), 256, 0, stream>>>(Xb, wqb, wkb, wvb, Qb, Kb, Vb);

  // fused RoPE (Q+K) + V transpose, one launch
  {
    int total = MTOT * 20 * 36 + 8 * 80 * S_;
    k_post<<<(total + 255) / 256, 256, 0, stream>>>(Qb, Kb, Vb, Vt, tab);
  }

  k_flash<<<1024, 256, 0, stream>>>(Qb, Kb, Vt, Ob);

  k_gemm_o<<<dim3(32, 9), 256, 0, stream>>>(Ob, wob, (float*)d_out, MTOT, HID_, HID_);
}